// Round 3
// baseline (3785.583 us; speedup 1.0000x reference)
//
#include <hip/hip_runtime.h>
#include <cstdint>
#include <cstddef>

#define BB 8
#define NN 8192
#define SS 2048
#define KNB 32

// Bit-exact squared distance matching numpy: (a-b) per component, squares,
// left-to-right sum, no FMA contraction.
__device__ __forceinline__ float sqdist_exact(float ax, float ay, float az,
                                              float bx, float by, float bz) {
#pragma clang fp contract(off)
    float dx = ax - bx;
    float dy = ay - by;
    float dz = az - bz;
    return (dx * dx + dy * dy) + dz * dz;
}

// DPP wave-64 reduce steps (gfx9 lineage: row_shr + row_bcast legal on CDNA4).
// u64 max step via DPP (2 dpp movs + u64 cmp/select, pure VALU). Identity 0
// is safe: keys are always non-negative (dist bits in the high half).
template <int CTRL>
__device__ __forceinline__ unsigned long long dpp_u64max_step(unsigned long long k) {
    int lo = __builtin_amdgcn_update_dpp(0, (int)(unsigned)(k & 0xffffffffu),
                                         CTRL, 0xf, 0xf, false);
    int hi = __builtin_amdgcn_update_dpp(0, (int)(unsigned)(k >> 32),
                                         CTRL, 0xf, 0xf, false);
    unsigned long long o = ((unsigned long long)(unsigned)hi << 32) | (unsigned)lo;
    return (o > k) ? o : k;
}
#define ROW_SHR1 0x111
#define ROW_SHR2 0x112
#define ROW_SHR4 0x114
#define ROW_SHR8 0x118
#define ROW_BC15 0x142
#define ROW_BC31 0x143

// full-wave min/max butterfly (init-time only, not on the hot path)
__device__ __forceinline__ void wave_minmax(float x, float& lo, float& hi) {
    float a = x, b = x;
#pragma unroll
    for (int off = 1; off < 64; off <<= 1) {
        a = fminf(a, __shfl_xor(a, off));
        b = fmaxf(b, __shfl_xor(b, off));
    }
    lo = a;
    hi = b;
}

// ---------------------------------------------------------------------------
// Weight transpose prep: w1T[c][64], w2T[j][64], w3T[j][128]
// ---------------------------------------------------------------------------
__global__ void prep_kernel(const float* __restrict__ w1, const float* __restrict__ w2,
                            const float* __restrict__ w3, float* __restrict__ w1T,
                            float* __restrict__ w2T, float* __restrict__ w3T) {
    for (int i = threadIdx.x; i < 192; i += 256) {
        int oc = i / 3, c = i % 3;
        w1T[c * 64 + oc] = w1[i];
    }
    for (int i = threadIdx.x; i < 4096; i += 256) {
        int oc = i >> 6, j = i & 63;
        w2T[j * 64 + oc] = w2[i];
    }
    for (int i = threadIdx.x; i < 8192; i += 256) {
        int oc = i >> 6, j = i & 63;
        w3T[j * 128 + oc] = w3[i];
    }
}

// spread 3-bit value to bit positions 0,3,6
__device__ __forceinline__ int part3(int v) {
    return (v & 1) | ((v & 2) << 2) | ((v & 4) << 4);
}

#define PT_LIST(X) X(0) X(1) X(2) X(3) X(4) X(5) X(6) X(7) \
                   X(8) X(9) X(10) X(11) X(12) X(13) X(14) X(15)

// ---------------------------------------------------------------------------
// FPS — R14b: per-brick cached argmax keys (R14 with the writelane fixed to a
// v_cndmask select — readlane results are wave-uniform SGPRs, so
// bkey = (lane==i) ? k : bkey parks them in lane i at VALU speed).
// R13's flaw (post-mortem): bricks were pruned against wave_bv (max over the
// wave's WHOLE 1024-pt octant), so mask!=0 nearly every iter and the full
// 110-inst in-wave reduce ran every iteration on the barrier's critical path.
// Here: lane i (<16) caches brick i's u64 argmax key (dist_bits<<32 | ~od).
// Prune tests brick i against ITS OWN max (key hi word) — the local FPS
// radius^2, ~10x tighter -> steady-state active bricks ~1-3 globally; most
// waves skip straight to the barrier with the cached waveKey. Only an updated
// brick re-runs ONE 6-step DPP u64-argmax chain (exact: unpruned bricks'
// dists are untouched, so cached keys stay exact). Wave key = 4-step DPP
// u64max over lanes 0..15 of the cached keys, only when mask!=0. Tie-break
// semantics identical (~od low word). Cross-wave tail, Morton sort, brick
// bboxes, update math unchanged from R13 (verified).
// ---------------------------------------------------------------------------
__global__ __attribute__((amdgpu_flat_work_group_size(512, 512),
                          amdgpu_waves_per_eu(2, 2)))
void fps_kernel(const float* __restrict__ xyz_all,
                float4* __restrict__ wsSorted,
                float4* __restrict__ wsCtr,
                float* __restrict__ out0) {
    const int b = blockIdx.x;
    const float* xyz = xyz_all + (size_t)b * NN * 3;
    float4* sorted = wsSorted + (size_t)b * NN;
    float4* ctr = wsCtr + (size_t)b * SS;
    float* o0 = out0 + (size_t)b * 3 * SS;

    __shared__ float xLds[NN];            // 32KB
    __shared__ float yLds[NN];            // 32KB
    __shared__ float zLds[NN];            // 32KB
    __shared__ float4 ctrLds[SS];         // 32KB
    __shared__ int cellCnt[512];
    __shared__ int cellBase[512];
    __shared__ unsigned long long red[2][8];

    const int tid = threadIdx.x;
    const int wid = tid >> 6;
    const int lane = tid & 63;

    // --- pass 1: per-Morton-cell counts (16 pts/thread) + stage xyz in LDS
    cellCnt[tid] = 0;
    __syncthreads();
    int cellReg[16];
#pragma unroll
    for (int j = 0; j < 16; ++j) {
        int p = tid + j * 512;
        float x = xyz[p * 3 + 0], y = xyz[p * 3 + 1], z = xyz[p * 3 + 2];
        xLds[p] = x; yLds[p] = y; zLds[p] = z;
        int qx = min(7, (int)(x * 8.0f));
        int qy = min(7, (int)(y * 8.0f));
        int qz = min(7, (int)(z * 8.0f));
        cellReg[j] = part3(qx) | (part3(qy) << 1) | (part3(qz) << 2);
        atomicAdd(&cellCnt[cellReg[j]], 1);
    }
    __syncthreads();
    int myCnt = cellCnt[tid];
    // inclusive Hillis-Steele scan over 512 cells (thread==cell)
    for (int off = 1; off < 512; off <<= 1) {
        int v = (tid >= off) ? cellCnt[tid - off] : 0;
        __syncthreads();
        cellCnt[tid] += v;
        __syncthreads();
    }
    cellBase[tid] = cellCnt[tid] - myCnt;
    __syncthreads();
    // --- pass 2: scatter to global ws in PLAIN Morton-slot order. The reader
    // (reg j, lane l <-> slot (wid*16+j)*64 + l) is coalesced directly.
#pragma unroll
    for (int j = 0; j < 16; ++j) {
        int p = tid + j * 512;
        float x = xLds[p], y = yLds[p], z = zLds[p];
        int pos = atomicAdd(&cellBase[cellReg[j]], 1);
        sorted[pos] = make_float4(x, y, z, __int_as_float(p));
    }
    __threadfence();
    __syncthreads();

    // --- load own 16 regs: reg i = Morton slots [(wid*16+i)*64, +64), lane l
    // holds slot (wid*16+i)*64 + l. Wave covers [wid*1024, +1024).
#define DECL_PT(i)                                      \
    float px##i, py##i, pz##i, dist##i;                 \
    int od##i;                                          \
    {                                                   \
        float4 v = sorted[(wid * 16 + i) * 64 + lane];  \
        px##i = v.x; py##i = v.y; pz##i = v.z;          \
        od##i = __float_as_int(v.w);                    \
        dist##i = 1e10f;                                \
    }
    PT_LIST(DECL_PT)

    // --- brick bboxes: brick i = reg i's 64 consecutive Morton slots.
    // Computed via shfl butterflies (one-time); lane i keeps brick i's bbox.
    float bbxlo = 0.f, bbxhi = 0.f, bbylo = 0.f, bbyhi = 0.f,
          bbzlo = 0.f, bbzhi = 0.f;
#define BRICK_BB(i)                                               \
    {                                                             \
        float xl, xh, yl, yh, zl, zh;                             \
        wave_minmax(px##i, xl, xh);                               \
        wave_minmax(py##i, yl, yh);                               \
        wave_minmax(pz##i, zl, zh);                               \
        if (lane == i) {                                          \
            bbxlo = xl; bbxhi = xh;                               \
            bbylo = yl; bbyhi = yh;                               \
            bbzlo = zl; bbzhi = zh;                               \
        }                                                         \
    }
    PT_LIST(BRICK_BB)

    float cx = xLds[0], cy = yLds[0], cz = zLds[0];
    if (tid == 0) ctrLds[0] = make_float4(cx, cy, cz, 0.0f);

    // per-brick cached argmax key: lane i (<16) holds brick i's key as
    // (hi=dist bits, lo=~od). Lanes 16..63 hold 0 (identity for u64max).
    // Init hi = 1e10 bits so every brick is active at s=1 (all keys get
    // rebuilt there before first use of the low word).
    int bkeyLo = 0;
    int bkeyHi = (lane < 16) ? (int)__float_as_uint(1e10f) : 0;

    unsigned long long waveKey =
        ((unsigned long long)__float_as_uint(1e10f) << 32) | 0xFFFFFFFFull;

    for (int s = 1; s < SS; ++s) {
        const int par = s & 1;
        // brick-granular exact prune: lane i<16 tests brick i's lower bound
        // against brick i's OWN cached max min-dist (key hi word). Skip is
        // exact: lb2 >= bv_i -> every d in brick >= every dist in brick ->
        // no dist changes -> cached key stays exact.
        float bv = __int_as_float(bkeyHi);
        float ddx = fmaxf(fmaxf(bbxlo - cx, cx - bbxhi), 0.0f);
        float ddy = fmaxf(fmaxf(bbylo - cy, cy - bbyhi), 0.0f);
        float ddz = fmaxf(fmaxf(bbzlo - cz, cz - bbzhi), 0.0f);
        float lb2 = (ddx * ddx + ddy * ddy) + ddz * ddz;
        bool act = (lane < 16) && (lb2 * 0.999f < bv);
        unsigned mask = (unsigned)__builtin_amdgcn_readfirstlane(
            (int)(unsigned)__ballot(act));
        if (mask) {
            // update dists of active bricks (cheap, parallel across regs)
#define UPD_BR(i)                                                     \
    if (mask & (1u << i)) {                                           \
        float d = sqdist_exact(px##i, py##i, pz##i, cx, cy, cz);      \
        dist##i = fminf(dist##i, d);                                  \
    }
            PT_LIST(UPD_BR)
            // rekey each updated brick: one 6-step DPP u64-argmax over its
            // 64 lanes; park result in lane i of (bkeyHi,bkeyLo) via
            // cndmask (klo/khi are wave-uniform after readlane).
#define REKEY_BR(i)                                                            \
    if (mask & (1u << i)) {                                                    \
        unsigned long long k =                                                 \
            ((unsigned long long)__float_as_uint(dist##i) << 32) |             \
            (unsigned)(~(unsigned)od##i);                                      \
        k = dpp_u64max_step<ROW_SHR1>(k);                                      \
        k = dpp_u64max_step<ROW_SHR2>(k);                                      \
        k = dpp_u64max_step<ROW_SHR4>(k);                                      \
        k = dpp_u64max_step<ROW_SHR8>(k);                                      \
        k = dpp_u64max_step<ROW_BC15>(k);                                      \
        k = dpp_u64max_step<ROW_BC31>(k);                                      \
        int klo = __builtin_amdgcn_readlane((int)(unsigned)(k & 0xffffffffu), 63); \
        int khi = __builtin_amdgcn_readlane((int)(unsigned)(k >> 32), 63);     \
        bkeyLo = (lane == i) ? klo : bkeyLo;                                   \
        bkeyHi = (lane == i) ? khi : bkeyHi;                                   \
    }
            PT_LIST(REKEY_BR)
            // wave key = max over the 16 cached brick keys (lanes 0..15;
            // lanes 16+ are 0 = identity). 4-step row_shr -> lane 15.
            unsigned long long wk =
                ((unsigned long long)(unsigned)bkeyHi << 32) | (unsigned)bkeyLo;
            wk = dpp_u64max_step<ROW_SHR1>(wk);
            wk = dpp_u64max_step<ROW_SHR2>(wk);
            wk = dpp_u64max_step<ROW_SHR4>(wk);
            wk = dpp_u64max_step<ROW_SHR8>(wk);
            unsigned wlo = (unsigned)__builtin_amdgcn_readlane(
                (int)(unsigned)(wk & 0xffffffffu), 15);
            unsigned whi = (unsigned)__builtin_amdgcn_readlane(
                (int)(unsigned)(wk >> 32), 15);
            waveKey = ((unsigned long long)whi << 32) | wlo;
        }
        if (lane == 0) red[par][wid] = waveKey;
        __syncthreads();  // lgkm-only drain (no global ops in loop)
        // cross-wave reduce: ONE lane-indexed b64 read + 3 DPP row_shr u64-max
        // steps (lane 7 of each 16-row = max over slots 0..7); the winning
        // index is the low half of the max key -> one readlane, no ballot.
        unsigned long long k = red[par][lane & 7];
        k = dpp_u64max_step<ROW_SHR1>(k);
        k = dpp_u64max_step<ROW_SHR2>(k);
        k = dpp_u64max_step<ROW_SHR4>(k);
        unsigned blo = (unsigned)__builtin_amdgcn_readlane(
            (int)(unsigned)(k & 0xffffffffu), 7);
        int wiu = (int)(~blo);  // uniform (SGPR) winner index
        cx = xLds[wiu];  // 3 independent broadcast ds_read_b32
        cy = yLds[wiu];
        cz = zLds[wiu];
        if (tid == 0) ctrLds[s] = make_float4(cx, cy, cz, 0.0f);
    }

    // --- single coalesced write-out of all centers
    __syncthreads();
    for (int s = tid; s < SS; s += 512) {
        float4 c = ctrLds[s];
        o0[s] = c.x;
        o0[SS + s] = c.y;
        o0[2 * SS + s] = c.z;
        ctr[s] = c;
    }
}

// ---------------------------------------------------------------------------
// Fused ball-query + MLP + maxpool. Block = 128 threads (2 waves), 2 centers.
// LDS halved (R9): h2 reuses h1's buffer in place -> ~17KB -> ~9 blocks/CU.
// ---------------------------------------------------------------------------
__global__ __launch_bounds__(128) void bqmlp_kernel(const float* __restrict__ xyz_all,
                                                    const float4* __restrict__ wsCtr,
                                                    const float* __restrict__ w1T,
                                                    const float* __restrict__ b1,
                                                    const float* __restrict__ w2T,
                                                    const float* __restrict__ b2,
                                                    const float* __restrict__ w3T,
                                                    const float* __restrict__ b3,
                                                    float* __restrict__ out1) {
    const int b = blockIdx.x >> 10;            // 1024 blocks per batch
    const int s0 = (blockIdx.x & 1023) * 2;    // 2 centers per block
    const float* xyz = xyz_all + (size_t)b * NN * 3;

    __shared__ float relF[2 * KNB * 3];  // [64 rows][3]
    __shared__ float hT[64 * 64];        // [ch][row] — holds h1, then h2

    const int tid = threadIdx.x;
    const int cb = __builtin_amdgcn_readfirstlane(tid >> 6);  // wave id (uniform)
    const int l = tid & 63;

    // ---- ball query: wave cb handles center s0+cb
    {
        float4 cc = wsCtr[(size_t)b * SS + s0 + cb];
        float ccx = cc.x, ccy = cc.y, ccz = cc.z;
        const float R2 = (float)(0.2 * 0.2);
        int total = 0;
        float fx = 0.f, fy = 0.f, fz = 0.f;
        bool have = false;
        for (int chunk = 0; chunk < 128 && total < KNB; ++chunk) {
            int p = chunk * 64 + l;
            float x = xyz[p * 3 + 0], y = xyz[p * 3 + 1], z = xyz[p * 3 + 2];
            float d = sqdist_exact(ccx, ccy, ccz, x, y, z);
            bool hit = (d <= R2);
            unsigned long long mask = __ballot(hit);
            int cnt = __popcll(mask);
            if (cnt) {
                int pos = total + __popcll(mask & ((1ull << l) - 1ull));
                float rx = x - ccx, ry = y - ccy, rz = z - ccz;  // single subs: exact
                if (hit && pos < KNB) {
                    relF[(cb * KNB + pos) * 3 + 0] = rx;
                    relF[(cb * KNB + pos) * 3 + 1] = ry;
                    relF[(cb * KNB + pos) * 3 + 2] = rz;
                }
                if (hit && pos == 0) { fx = rx; fy = ry; fz = rz; have = true; }
                total += cnt;
            }
        }
        unsigned long long hm = __ballot(have);
        if (total < KNB) {
            int src = __ffsll((long long)hm) - 1;
            float gx = __shfl(fx, src), gy = __shfl(fy, src), gz = __shfl(fz, src);
            if (l >= total && l < KNB) {
                relF[(cb * KNB + l) * 3 + 0] = gx;
                relF[(cb * KNB + l) * 3 + 1] = gy;
                relF[(cb * KNB + l) * 3 + 2] = gz;
            }
        }
    }
    __syncthreads();

    const int r = l;  // row 0..63: rows 0..31 center s0, rows 32..63 center s0+1

    // ---- layer 1: rel(3) -> 64, thread covers ch block cb*32..+31 for row r
    {
        float rx = relF[r * 3 + 0], ry = relF[r * 3 + 1], rz = relF[r * 3 + 2];
#pragma unroll
        for (int i = 0; i < 32; ++i) {
            int ch = cb * 32 + i;
            float h = b1[ch];
            h = fmaf(rx, w1T[0 * 64 + ch], h);
            h = fmaf(ry, w1T[1 * 64 + ch], h);
            h = fmaf(rz, w1T[2 * 64 + ch], h);
            hT[ch * 64 + r] = fmaxf(h, 0.0f);
        }
    }
    __syncthreads();

    // ---- layer 2: 64 -> 64 (reads h1 from hT; after barrier, h2 overwrites)
    {
        float acc[32];
#pragma unroll
        for (int i = 0; i < 32; ++i) acc[i] = b2[cb * 32 + i];
#pragma unroll 4
        for (int j = 0; j < 64; ++j) {
            float a = hT[j * 64 + r];
            const float* wrow = w2T + j * 64 + cb * 32;
#pragma unroll
            for (int i = 0; i < 32; ++i) acc[i] = fmaf(a, wrow[i], acc[i]);
        }
        __syncthreads();  // all h1 reads complete before overwrite
#pragma unroll
        for (int i = 0; i < 32; ++i) hT[(cb * 32 + i) * 64 + r] = fmaxf(acc[i], 0.0f);
    }
    __syncthreads();

    // ---- layer 3: 64 -> 128, fused relu + maxpool over the 32 rows/center
    {
        float acc[64];
#pragma unroll
        for (int i = 0; i < 64; ++i) acc[i] = b3[cb * 64 + i];
#pragma unroll 2
        for (int j = 0; j < 64; ++j) {
            float a = hT[j * 64 + r];
            const float* wrow = w3T + j * 128 + cb * 64;
#pragma unroll
            for (int i = 0; i < 64; ++i) acc[i] = fmaf(a, wrow[i], acc[i]);
        }
#pragma unroll
        for (int i = 0; i < 64; ++i) {
            float v = fmaxf(acc[i], 0.0f);
            v = fmaxf(v, __shfl_xor(v, 1));
            v = fmaxf(v, __shfl_xor(v, 2));
            v = fmaxf(v, __shfl_xor(v, 4));
            v = fmaxf(v, __shfl_xor(v, 8));
            v = fmaxf(v, __shfl_xor(v, 16));
            acc[i] = v;
        }
        if ((l & 31) == 0) {
            int sA = s0 + (l >> 5);
            float* op = out1 + ((size_t)b * 128 + cb * 64) * SS + sA;
#pragma unroll
            for (int i = 0; i < 64; ++i) op[(size_t)i * SS] = acc[i];
        }
    }
}

extern "C" void kernel_launch(void* const* d_in, const int* in_sizes, int n_in,
                              void* d_out, int out_size, void* d_ws, size_t ws_size,
                              hipStream_t stream) {
    (void)in_sizes; (void)n_in; (void)out_size; (void)ws_size;
    const float* xyz = (const float*)d_in[0];
    // d_in[1] = features : unused by the reference
    const float* w1 = (const float*)d_in[2];
    const float* b1 = (const float*)d_in[3];
    const float* w2 = (const float*)d_in[4];
    const float* b2 = (const float*)d_in[5];
    const float* w3 = (const float*)d_in[6];
    const float* b3 = (const float*)d_in[7];
    float* out = (float*)d_out;

    // workspace layout
    float4* wsCtr = (float4*)d_ws;              // B*S float4      (256 KB)
    float4* wsSorted = wsCtr + BB * SS;         // B*N float4      (1 MB)
    float* w1T = (float*)(wsSorted + BB * NN);  // 192 f
    float* w2T = w1T + 192;                     // 4096 f
    float* w3T = w2T + 4096;                    // 8192 f

    prep_kernel<<<1, 256, 0, stream>>>(w1, w2, w3, w1T, w2T, w3T);
    fps_kernel<<<BB, 512, 0, stream>>>(xyz, wsSorted, wsCtr, out);
    bqmlp_kernel<<<BB * (SS / 2), 128, 0, stream>>>(xyz, wsCtr, w1T, b1, w2T, b2,
                                                    w3T, b3, out + BB * 3 * SS);
}

// Round 4
// 2508.300 us; speedup vs baseline: 1.5092x; 1.5092x over previous
//
#include <hip/hip_runtime.h>
#include <cstdint>
#include <cstddef>

#define BB 8
#define NN 8192
#define SS 2048
#define KNB 32

// Bit-exact squared distance matching numpy: (a-b) per component, squares,
// left-to-right sum, no FMA contraction.
__device__ __forceinline__ float sqdist_exact(float ax, float ay, float az,
                                              float bx, float by, float bz) {
#pragma clang fp contract(off)
    float dx = ax - bx;
    float dy = ay - by;
    float dz = az - bz;
    return (dx * dx + dy * dy) + dz * dz;
}

// u64 max (compare-select, 3 VALU insts, branchless)
__device__ __forceinline__ unsigned long long u64max(unsigned long long a,
                                                     unsigned long long b) {
    return (a > b) ? a : b;
}

// DPP wave-64 reduce steps (gfx9 lineage: row_shr + row_bcast legal on CDNA4).
// u64 max step via DPP (2 dpp movs + u64 cmp/select, pure VALU). Identity 0
// is safe: keys are always non-negative (dist bits in the high half).
template <int CTRL>
__device__ __forceinline__ unsigned long long dpp_u64max_step(unsigned long long k) {
    int lo = __builtin_amdgcn_update_dpp(0, (int)(unsigned)(k & 0xffffffffu),
                                         CTRL, 0xf, 0xf, false);
    int hi = __builtin_amdgcn_update_dpp(0, (int)(unsigned)(k >> 32),
                                         CTRL, 0xf, 0xf, false);
    unsigned long long o = ((unsigned long long)(unsigned)hi << 32) | (unsigned)lo;
    return (o > k) ? o : k;
}
#define ROW_SHR1 0x111
#define ROW_SHR2 0x112
#define ROW_SHR4 0x114
#define ROW_SHR8 0x118
#define ROW_BC15 0x142
#define ROW_BC31 0x143

// full-wave min/max butterfly (init-time only, not on the hot path)
__device__ __forceinline__ void wave_minmax(float x, float& lo, float& hi) {
    float a = x, b = x;
#pragma unroll
    for (int off = 1; off < 64; off <<= 1) {
        a = fminf(a, __shfl_xor(a, off));
        b = fmaxf(b, __shfl_xor(b, off));
    }
    lo = a;
    hi = b;
}

// ---------------------------------------------------------------------------
// Weight transpose prep: w1T[c][64], w2T[j][64], w3T[j][128]
// ---------------------------------------------------------------------------
__global__ void prep_kernel(const float* __restrict__ w1, const float* __restrict__ w2,
                            const float* __restrict__ w3, float* __restrict__ w1T,
                            float* __restrict__ w2T, float* __restrict__ w3T) {
    for (int i = threadIdx.x; i < 192; i += 256) {
        int oc = i / 3, c = i % 3;
        w1T[c * 64 + oc] = w1[i];
    }
    for (int i = threadIdx.x; i < 4096; i += 256) {
        int oc = i >> 6, j = i & 63;
        w2T[j * 64 + oc] = w2[i];
    }
    for (int i = threadIdx.x; i < 8192; i += 256) {
        int oc = i >> 6, j = i & 63;
        w3T[j * 128 + oc] = w3[i];
    }
}

// spread 3-bit value to bit positions 0,3,6
__device__ __forceinline__ int part3(int v) {
    return (v & 1) | ((v & 2) << 2) | ((v & 4) << 4);
}

#define PT_LIST(X) X(0) X(1) X(2) X(3) X(4) X(5) X(6) X(7) \
                   X(8) X(9) X(10) X(11) X(12) X(13) X(14) X(15)

// ---------------------------------------------------------------------------
// FPS — R15. Post-mortem of R14b (3460us, 2x regression): 32 wave-uniform
// s_cbranch-guarded regions/iter (branch bubbles ~50-70cy each) + per-brick
// 6-step DPP chains in separate if-blocks (serial, un-interleavable, ~110cy
// each, up to 16 at s=1) made the busiest wave's path LONGER than R1's
// constant joint reduce. Critical path = max over waves, so that's a pure
// loss. R15 = single branch per iteration:
//   - per-brick skip bound ub_i maintained INCREMENTALLY (corner-distance
//     bound, pure per-lane VALU, never a reduce): ub_i = min(ub_i,
//     cornerDist2*1.0009). Valid: after a full update, every dist in brick
//     <= d <= corner2; for pruned bricks d >= dist so the unconditional
//     update is a numerical no-op and ub stays an upper bound.
//   - ballot(lb2*0.999 < ub_i) == 0 -> wave skips update+reduce entirely
//     (one branch; fires strictly more often than the R12 wave-bbox test).
//   - busy path is BRANCHLESS: full 16-reg update, then ONE joint u64
//     argmax reduce: keys (dist<<32 | ~od) (~od precomputed at init), 4-level
//     ILP tree over 16 regs, one 6-step DPP u64max chain, lane63 writes red
//     directly; 2 readlanes refresh the cached waveKey off the critical path.
//     Replaces R1's two-pass reduce (fmax chain+DPP+readlane+idx chain+DPP+
//     readlane ~400cy) with ~200cy. Ordering semantics identical (max dist,
//     then min original index via ~od), same as the verified cross-wave key.
// Cross-wave tail, Morton sort, brick bboxes, update math unchanged
// (verified in R1/R3 correctness runs).
// ---------------------------------------------------------------------------
__global__ __attribute__((amdgpu_flat_work_group_size(512, 512),
                          amdgpu_waves_per_eu(2, 2)))
void fps_kernel(const float* __restrict__ xyz_all,
                float4* __restrict__ wsSorted,
                float4* __restrict__ wsCtr,
                float* __restrict__ out0) {
    const int b = blockIdx.x;
    const float* xyz = xyz_all + (size_t)b * NN * 3;
    float4* sorted = wsSorted + (size_t)b * NN;
    float4* ctr = wsCtr + (size_t)b * SS;
    float* o0 = out0 + (size_t)b * 3 * SS;

    __shared__ float xLds[NN];            // 32KB
    __shared__ float yLds[NN];            // 32KB
    __shared__ float zLds[NN];            // 32KB
    __shared__ float4 ctrLds[SS];         // 32KB
    __shared__ int cellCnt[512];
    __shared__ int cellBase[512];
    __shared__ unsigned long long red[2][8];

    const int tid = threadIdx.x;
    const int wid = tid >> 6;
    const int lane = tid & 63;

    // --- pass 1: per-Morton-cell counts (16 pts/thread) + stage xyz in LDS
    cellCnt[tid] = 0;
    __syncthreads();
    int cellReg[16];
#pragma unroll
    for (int j = 0; j < 16; ++j) {
        int p = tid + j * 512;
        float x = xyz[p * 3 + 0], y = xyz[p * 3 + 1], z = xyz[p * 3 + 2];
        xLds[p] = x; yLds[p] = y; zLds[p] = z;
        int qx = min(7, (int)(x * 8.0f));
        int qy = min(7, (int)(y * 8.0f));
        int qz = min(7, (int)(z * 8.0f));
        cellReg[j] = part3(qx) | (part3(qy) << 1) | (part3(qz) << 2);
        atomicAdd(&cellCnt[cellReg[j]], 1);
    }
    __syncthreads();
    int myCnt = cellCnt[tid];
    // inclusive Hillis-Steele scan over 512 cells (thread==cell)
    for (int off = 1; off < 512; off <<= 1) {
        int v = (tid >= off) ? cellCnt[tid - off] : 0;
        __syncthreads();
        cellCnt[tid] += v;
        __syncthreads();
    }
    cellBase[tid] = cellCnt[tid] - myCnt;
    __syncthreads();
    // --- pass 2: scatter to global ws in PLAIN Morton-slot order. The reader
    // (reg j, lane l <-> slot (wid*16+j)*64 + l) is coalesced directly.
#pragma unroll
    for (int j = 0; j < 16; ++j) {
        int p = tid + j * 512;
        float x = xLds[p], y = yLds[p], z = zLds[p];
        int pos = atomicAdd(&cellBase[cellReg[j]], 1);
        sorted[pos] = make_float4(x, y, z, __int_as_float(p));
    }
    __threadfence();
    __syncthreads();

    // --- load own 16 regs: reg i = Morton slots [(wid*16+i)*64, +64), lane l
    // holds slot (wid*16+i)*64 + l. Wave covers [wid*1024, +1024).
    // nd##i = ~original_index, precomputed for key packing.
#define DECL_PT(i)                                      \
    float px##i, py##i, pz##i, dist##i;                 \
    int nd##i;                                          \
    {                                                   \
        float4 v = sorted[(wid * 16 + i) * 64 + lane];  \
        px##i = v.x; py##i = v.y; pz##i = v.z;          \
        nd##i = ~__float_as_int(v.w);                   \
        dist##i = 1e10f;                                \
    }
    PT_LIST(DECL_PT)

    // --- brick bboxes: brick i = reg i's 64 consecutive Morton slots.
    // Computed via shfl butterflies (one-time); lane i keeps brick i's bbox.
    float bbxlo = 0.f, bbxhi = 0.f, bbylo = 0.f, bbyhi = 0.f,
          bbzlo = 0.f, bbzhi = 0.f;
#define BRICK_BB(i)                                               \
    {                                                             \
        float xl, xh, yl, yh, zl, zh;                             \
        wave_minmax(px##i, xl, xh);                               \
        wave_minmax(py##i, yl, yh);                               \
        wave_minmax(pz##i, zl, zh);                               \
        if (lane == i) {                                          \
            bbxlo = xl; bbxhi = xh;                               \
            bbylo = yl; bbyhi = yh;                               \
            bbzlo = zl; bbzhi = zh;                               \
        }                                                         \
    }
    PT_LIST(BRICK_BB)

    float cx = xLds[0], cy = yLds[0], cz = zLds[0];
    if (tid == 0) ctrLds[0] = make_float4(cx, cy, cz, 0.0f);

    // per-brick incremental upper bound on max dist in brick (lane i < 16)
    float ubr = 1e10f;

    unsigned long long waveKey =
        ((unsigned long long)__float_as_uint(1e10f) << 32) | 0xFFFFFFFFull;

    for (int s = 1; s < SS; ++s) {
        const int par = s & 1;
        // brick-granular prune: lane i<16 tests brick i's lower bound to the
        // center against brick i's incremental upper bound ub_i.
        float ddx = fmaxf(fmaxf(bbxlo - cx, cx - bbxhi), 0.0f);
        float ddy = fmaxf(fmaxf(bbylo - cy, cy - bbyhi), 0.0f);
        float ddz = fmaxf(fmaxf(bbzlo - cz, cz - bbzhi), 0.0f);
        float lb2 = (ddx * ddx + ddy * ddy) + ddz * ddz;
        bool act = (lane < 16) && (lb2 * 0.999f < ubr);
        if (__ballot(act)) {
            // corner-distance bound of this center to brick (lane i < 16):
            // cornerDist^2 >= d(p,c)^2 for every p in the brick.
            float cdx = fmaxf(cx - bbxlo, bbxhi - cx);
            float cdy = fmaxf(cy - bbylo, bbyhi - cy);
            float cdz = fmaxf(cz - bbzlo, bbzhi - cz);
            float corner2 = (cdx * cdx + cdy * cdy) + cdz * cdz;
            ubr = fminf(ubr, corner2 * 1.0009f);
            // branchless full update (pruned bricks: d >= dist, no-op)
#define UPD_PT(i)                                                     \
    {                                                                 \
        float d = sqdist_exact(px##i, py##i, pz##i, cx, cy, cz);      \
        dist##i = fminf(dist##i, d);                                  \
    }
            PT_LIST(UPD_PT)
            // joint u64 argmax: key = (dist bits << 32) | ~od
#define KEY_PT(i)                                                     \
    unsigned long long k##i =                                         \
        ((unsigned long long)__float_as_uint(dist##i) << 32) |        \
        (unsigned)nd##i;
            PT_LIST(KEY_PT)
            // 4-level ILP tree over the 16 per-lane keys
            unsigned long long t0 = u64max(k0, k1), t1 = u64max(k2, k3),
                               t2 = u64max(k4, k5), t3 = u64max(k6, k7),
                               t4 = u64max(k8, k9), t5 = u64max(k10, k11),
                               t6 = u64max(k12, k13), t7 = u64max(k14, k15);
            unsigned long long u0 = u64max(t0, t1), u1 = u64max(t2, t3),
                               u2 = u64max(t4, t5), u3 = u64max(t6, t7);
            unsigned long long K = u64max(u64max(u0, u1), u64max(u2, u3));
            // cross-lane: 6-step DPP u64max chain -> lane 63
            K = dpp_u64max_step<ROW_SHR1>(K);
            K = dpp_u64max_step<ROW_SHR2>(K);
            K = dpp_u64max_step<ROW_SHR4>(K);
            K = dpp_u64max_step<ROW_SHR8>(K);
            K = dpp_u64max_step<ROW_BC15>(K);
            K = dpp_u64max_step<ROW_BC31>(K);
            if (lane == 63) red[par][wid] = K;
            // refresh cached uniform key (off the critical path — only
            // needed by future quiet iterations)
            unsigned klo = (unsigned)__builtin_amdgcn_readlane(
                (int)(unsigned)(K & 0xffffffffu), 63);
            unsigned khi = (unsigned)__builtin_amdgcn_readlane(
                (int)(unsigned)(K >> 32), 63);
            waveKey = ((unsigned long long)khi << 32) | klo;
        } else {
            if (lane == 0) red[par][wid] = waveKey;
        }
        __syncthreads();  // lgkm-only drain (no global ops in loop)
        // cross-wave reduce: ONE lane-indexed b64 read + 3 DPP row_shr u64-max
        // steps (lane 7 of each 16-row = max over slots 0..7); the winning
        // index is the low half of the max key -> one readlane, no ballot.
        unsigned long long k = red[par][lane & 7];
        k = dpp_u64max_step<ROW_SHR1>(k);
        k = dpp_u64max_step<ROW_SHR2>(k);
        k = dpp_u64max_step<ROW_SHR4>(k);
        unsigned blo = (unsigned)__builtin_amdgcn_readlane(
            (int)(unsigned)(k & 0xffffffffu), 7);
        int wiu = (int)(~blo);  // uniform (SGPR) winner index
        cx = xLds[wiu];  // 3 independent broadcast ds_read_b32
        cy = yLds[wiu];
        cz = zLds[wiu];
        if (tid == 0) ctrLds[s] = make_float4(cx, cy, cz, 0.0f);
    }

    // --- single coalesced write-out of all centers
    __syncthreads();
    for (int s = tid; s < SS; s += 512) {
        float4 c = ctrLds[s];
        o0[s] = c.x;
        o0[SS + s] = c.y;
        o0[2 * SS + s] = c.z;
        ctr[s] = c;
    }
}

// ---------------------------------------------------------------------------
// Fused ball-query + MLP + maxpool. Block = 128 threads (2 waves), 2 centers.
// LDS halved (R9): h2 reuses h1's buffer in place -> ~17KB -> ~9 blocks/CU.
// ---------------------------------------------------------------------------
__global__ __launch_bounds__(128) void bqmlp_kernel(const float* __restrict__ xyz_all,
                                                    const float4* __restrict__ wsCtr,
                                                    const float* __restrict__ w1T,
                                                    const float* __restrict__ b1,
                                                    const float* __restrict__ w2T,
                                                    const float* __restrict__ b2,
                                                    const float* __restrict__ w3T,
                                                    const float* __restrict__ b3,
                                                    float* __restrict__ out1) {
    const int b = blockIdx.x >> 10;            // 1024 blocks per batch
    const int s0 = (blockIdx.x & 1023) * 2;    // 2 centers per block
    const float* xyz = xyz_all + (size_t)b * NN * 3;

    __shared__ float relF[2 * KNB * 3];  // [64 rows][3]
    __shared__ float hT[64 * 64];        // [ch][row] — holds h1, then h2

    const int tid = threadIdx.x;
    const int cb = __builtin_amdgcn_readfirstlane(tid >> 6);  // wave id (uniform)
    const int l = tid & 63;

    // ---- ball query: wave cb handles center s0+cb
    {
        float4 cc = wsCtr[(size_t)b * SS + s0 + cb];
        float ccx = cc.x, ccy = cc.y, ccz = cc.z;
        const float R2 = (float)(0.2 * 0.2);
        int total = 0;
        float fx = 0.f, fy = 0.f, fz = 0.f;
        bool have = false;
        for (int chunk = 0; chunk < 128 && total < KNB; ++chunk) {
            int p = chunk * 64 + l;
            float x = xyz[p * 3 + 0], y = xyz[p * 3 + 1], z = xyz[p * 3 + 2];
            float d = sqdist_exact(ccx, ccy, ccz, x, y, z);
            bool hit = (d <= R2);
            unsigned long long mask = __ballot(hit);
            int cnt = __popcll(mask);
            if (cnt) {
                int pos = total + __popcll(mask & ((1ull << l) - 1ull));
                float rx = x - ccx, ry = y - ccy, rz = z - ccz;  // single subs: exact
                if (hit && pos < KNB) {
                    relF[(cb * KNB + pos) * 3 + 0] = rx;
                    relF[(cb * KNB + pos) * 3 + 1] = ry;
                    relF[(cb * KNB + pos) * 3 + 2] = rz;
                }
                if (hit && pos == 0) { fx = rx; fy = ry; fz = rz; have = true; }
                total += cnt;
            }
        }
        unsigned long long hm = __ballot(have);
        if (total < KNB) {
            int src = __ffsll((long long)hm) - 1;
            float gx = __shfl(fx, src), gy = __shfl(fy, src), gz = __shfl(fz, src);
            if (l >= total && l < KNB) {
                relF[(cb * KNB + l) * 3 + 0] = gx;
                relF[(cb * KNB + l) * 3 + 1] = gy;
                relF[(cb * KNB + l) * 3 + 2] = gz;
            }
        }
    }
    __syncthreads();

    const int r = l;  // row 0..63: rows 0..31 center s0, rows 32..63 center s0+1

    // ---- layer 1: rel(3) -> 64, thread covers ch block cb*32..+31 for row r
    {
        float rx = relF[r * 3 + 0], ry = relF[r * 3 + 1], rz = relF[r * 3 + 2];
#pragma unroll
        for (int i = 0; i < 32; ++i) {
            int ch = cb * 32 + i;
            float h = b1[ch];
            h = fmaf(rx, w1T[0 * 64 + ch], h);
            h = fmaf(ry, w1T[1 * 64 + ch], h);
            h = fmaf(rz, w1T[2 * 64 + ch], h);
            hT[ch * 64 + r] = fmaxf(h, 0.0f);
        }
    }
    __syncthreads();

    // ---- layer 2: 64 -> 64 (reads h1 from hT; after barrier, h2 overwrites)
    {
        float acc[32];
#pragma unroll
        for (int i = 0; i < 32; ++i) acc[i] = b2[cb * 32 + i];
#pragma unroll 4
        for (int j = 0; j < 64; ++j) {
            float a = hT[j * 64 + r];
            const float* wrow = w2T + j * 64 + cb * 32;
#pragma unroll
            for (int i = 0; i < 32; ++i) acc[i] = fmaf(a, wrow[i], acc[i]);
        }
        __syncthreads();  // all h1 reads complete before overwrite
#pragma unroll
        for (int i = 0; i < 32; ++i) hT[(cb * 32 + i) * 64 + r] = fmaxf(acc[i], 0.0f);
    }
    __syncthreads();

    // ---- layer 3: 64 -> 128, fused relu + maxpool over the 32 rows/center
    {
        float acc[64];
#pragma unroll
        for (int i = 0; i < 64; ++i) acc[i] = b3[cb * 64 + i];
#pragma unroll 2
        for (int j = 0; j < 64; ++j) {
            float a = hT[j * 64 + r];
            const float* wrow = w3T + j * 128 + cb * 64;
#pragma unroll
            for (int i = 0; i < 64; ++i) acc[i] = fmaf(a, wrow[i], acc[i]);
        }
#pragma unroll
        for (int i = 0; i < 64; ++i) {
            float v = fmaxf(acc[i], 0.0f);
            v = fmaxf(v, __shfl_xor(v, 1));
            v = fmaxf(v, __shfl_xor(v, 2));
            v = fmaxf(v, __shfl_xor(v, 4));
            v = fmaxf(v, __shfl_xor(v, 8));
            v = fmaxf(v, __shfl_xor(v, 16));
            acc[i] = v;
        }
        if ((l & 31) == 0) {
            int sA = s0 + (l >> 5);
            float* op = out1 + ((size_t)b * 128 + cb * 64) * SS + sA;
#pragma unroll
            for (int i = 0; i < 64; ++i) op[(size_t)i * SS] = acc[i];
        }
    }
}

extern "C" void kernel_launch(void* const* d_in, const int* in_sizes, int n_in,
                              void* d_out, int out_size, void* d_ws, size_t ws_size,
                              hipStream_t stream) {
    (void)in_sizes; (void)n_in; (void)out_size; (void)ws_size;
    const float* xyz = (const float*)d_in[0];
    // d_in[1] = features : unused by the reference
    const float* w1 = (const float*)d_in[2];
    const float* b1 = (const float*)d_in[3];
    const float* w2 = (const float*)d_in[4];
    const float* b2 = (const float*)d_in[5];
    const float* w3 = (const float*)d_in[6];
    const float* b3 = (const float*)d_in[7];
    float* out = (float*)d_out;

    // workspace layout
    float4* wsCtr = (float4*)d_ws;              // B*S float4      (256 KB)
    float4* wsSorted = wsCtr + BB * SS;         // B*N float4      (1 MB)
    float* w1T = (float*)(wsSorted + BB * NN);  // 192 f
    float* w2T = w1T + 192;                     // 4096 f
    float* w3T = w2T + 4096;                    // 8192 f

    prep_kernel<<<1, 256, 0, stream>>>(w1, w2, w3, w1T, w2T, w3T);
    fps_kernel<<<BB, 512, 0, stream>>>(xyz, wsSorted, wsCtr, out);
    bqmlp_kernel<<<BB * (SS / 2), 128, 0, stream>>>(xyz, wsCtr, w1T, b1, w2T, b2,
                                                    w3T, b3, out + BB * 3 * SS);
}